// Round 3
// baseline (204.044 us; speedup 1.0000x reference)
//
#include <hip/hip_runtime.h>

// ContrastiveLoss: B=8192, D=128, T=0.1, SINGLE_POS=False.
// Key algebra:
//   b = tt ^ tp (1 bit/row).  pos_mask|neg_mask(i,j) <=> b_i != b_j.
//   denom uses only E_i = sum_{b_j != b_i} exp(10*s_ij)  (Ep+En merged).
//   Ls_i = sum_{cls_j == c_i^1} s_ij = g_i . S_{c_i^1}   (linear -> precomputed class sums).
//   loss = -(1/B) * sum_i valid_i * (10*Ls_i - pcnt_i*log(E_i)) / pcnt_i,
//   pcnt = cnt[c^1], ncnt = cnt[c^2] (global class histogram).

#define NB 8192
#define ND 128
#define EXPK 14.426950408889634f   // 10 * log2(e)

#define ITILE 128
#define NIB (NB / ITILE)     // 64 i-tiles
#define JSPLIT 32            // 32 j-ranges of 256 cols (16 MFMA j-tiles each)
#define JTPB 16              // j-tiles per block
#define SIMB (NIB * JSPLIT)  // 2048 sim blocks
#define CSB 32               // fused class-sum blocks
#define HISTB 32             // hist blocks in prep

typedef __attribute__((ext_vector_type(8))) short short8;
typedef __attribute__((ext_vector_type(4))) float f32x4;

// ws layout (bytes); ws >= 3.7 MB (prior rounds used that much)
#define OFF_G    0                    // 8192*128 bf16 = 2 MB
#define OFF_EPP  2097152              // 32*8192 f32 = 1 MB
#define OFF_SP   3145728              // 64*4*128 f32 = 128 KB (class-sum partials)
#define OFF_CLS  3276800              // 8192 u8
#define OFF_CNT  3284992              // 32*4 i32 (hist partials)

__device__ __forceinline__ unsigned short f2bf(float x) {
    unsigned int u = __float_as_uint(x);
    return (unsigned short)((u + 0x7FFFu + ((u >> 16) & 1u)) >> 16);  // RNE
}
__device__ __forceinline__ float bf2f(unsigned short h) {
    return __uint_as_float(((unsigned int)h) << 16);
}
__device__ __forceinline__ float fast_exp2(float x) {
#if __has_builtin(__builtin_amdgcn_exp2f)
    return __builtin_amdgcn_exp2f(x);
#else
    return exp2f(x);
#endif
}

// Blocks 0..2047: normalize 4 rows each (wave/row) -> bf16 G.
// Blocks 2048..2079: 256-row gather + LDS hist -> cntP partials (no global atomics).
__global__ __launch_bounds__(256) void prep_kernel(
    const float* __restrict__ F, const int* __restrict__ dix,
    const int* __restrict__ tt, const int* __restrict__ tp,
    unsigned short* __restrict__ G, unsigned char* __restrict__ cls,
    int* __restrict__ cntP, float* __restrict__ out)
{
    if (blockIdx.x < 2048) {
        const int row  = blockIdx.x * 4 + (threadIdx.x >> 6);
        const int lane = threadIdx.x & 63;
        const float2 v = *(const float2*)(F + row * ND + lane * 2);
        float ss = v.x * v.x + v.y * v.y;
        #pragma unroll
        for (int m = 1; m < 64; m <<= 1) ss += __shfl_xor(ss, m, 64);
        const float inv = rsqrtf(fmaxf(ss, 1e-24f));
        ushort2 st;
        st.x = f2bf(v.x * inv);
        st.y = f2bf(v.y * inv);
        *(ushort2*)(G + row * ND + lane * 2) = st;
    } else {
        __shared__ int lh[4];
        const int h   = blockIdx.x - 2048;
        const int tid = threadIdx.x;
        if (tid < 4) lh[tid] = 0;
        __syncthreads();
        const int row = h * 256 + tid;
        const int ix  = dix[row];
        const int c   = ((tt[ix] & 1) << 1) | (tp[ix] & 1);
        cls[row] = (unsigned char)c;
        atomicAdd(&lh[c], 1);
        __syncthreads();
        if (tid < 4) cntP[h * 4 + tid] = lh[tid];
        if (h == 0 && tid == 4) *out = 0.0f;
    }
}

// Blocks 0..2047: 64 i-tiles (128 rows) x 32 j-ranges (256 cols). ib is the
// minor grid index so co-resident blocks share the B stream (L1 hits).
// Blocks 2048..2079: class-sum S_c partials (independent work, fused to
// avoid a 4th launch).
__global__ __launch_bounds__(256, 6) void sim_kernel(
    const unsigned short* __restrict__ G,
    const unsigned char* __restrict__ cls,
    float* __restrict__ EpP, float* __restrict__ Sp)
{
    if (blockIdx.x >= SIMB) {
        // ---- class-sum: 32 blocks x 256 rows ----
        const int b    = blockIdx.x - SIMB;
        const int dim  = threadIdx.x & 127;
        const int half = threadIdx.x >> 7;
        const int base = b * 256 + half * 128;
        float a0 = 0.f, a1 = 0.f, a2 = 0.f, a3 = 0.f;
        for (int k = 0; k < 128; ++k) {
            const int row = base + k;
            const float g = bf2f(G[row * ND + dim]);
            const int c = cls[row];            // wave-uniform
            a0 += (c == 0) ? g : 0.f;
            a1 += (c == 1) ? g : 0.f;
            a2 += (c == 2) ? g : 0.f;
            a3 += (c == 3) ? g : 0.f;
        }
        float* s = Sp + (b * 2 + half) * 512 + dim;
        s[0] = a0; s[128] = a1; s[256] = a2; s[384] = a3;
        return;
    }

    const int ib   = blockIdx.x & (NIB - 1);
    const int jb   = blockIdx.x >> 6;
    const int wave = threadIdx.x >> 6;
    const int lane = threadIdx.x & 63;
    const int q    = lane >> 4;
    const int l16  = lane & 15;
    const int ri   = ib * ITILE + wave * 32;   // this wave's 32 rows

    // A-fragments: A[m=l16][k=q*8+j], chunk c covers k in [32c, 32c+32).
    short8 A[2][4];
    #pragma unroll
    for (int t = 0; t < 2; ++t)
        #pragma unroll
        for (int c = 0; c < 4; ++c)
            A[t][c] = *(const short8*)(G + (ri + 16 * t + l16) * ND + c * 32 + q * 8);

    // Packed b-bits of this lane's 8 output rows (C/D row = 16t + 4q + r).
    int B8 = 0;
    #pragma unroll
    for (int t = 0; t < 2; ++t)
        #pragma unroll
        for (int r = 0; r < 4; ++r) {
            const int ci = cls[ri + 16 * t + 4 * q + r];
            B8 |= (((ci + 1) >> 1) & 1) << (t * 4 + r);
        }

    float E[8];
    #pragma unroll
    for (int i = 0; i < 8; ++i) E[i] = 0.f;

    const int jt0 = jb * JTPB;
    for (int k = 0; k < JTPB; ++k) {
        const int j0 = (jt0 + k) * 16;
        short8 Bf[4];
        #pragma unroll
        for (int c = 0; c < 4; ++c)
            Bf[c] = *(const short8*)(G + (j0 + l16) * ND + c * 32 + q * 8);
        const int c8 = cls[j0 + l16];
        const int X  = B8 ^ (((c8 + 1) & 2) ? 255 : 0);  // bit idx set <=> b_i != b_j

        #pragma unroll
        for (int t = 0; t < 2; ++t) {
            f32x4 acc = {0.f, 0.f, 0.f, 0.f};
            #pragma unroll
            for (int c = 0; c < 4; ++c)
                acc = __builtin_amdgcn_mfma_f32_16x16x32_bf16(A[t][c], Bf[c], acc, 0, 0, 0);
            #pragma unroll
            for (int r = 0; r < 4; ++r) {
                const float e = fast_exp2(acc[r] * EXPK);
                const int idx = t * 4 + r;
                E[idx] += (X & (1 << idx)) ? e : 0.f;
            }
        }
    }

    // Sum over the 16 column-lanes (xor bits 0..3 stay within the q-group).
    #pragma unroll
    for (int m = 1; m < 16; m <<= 1)
        #pragma unroll
        for (int i = 0; i < 8; ++i) E[i] += __shfl_xor(E[i], m, 64);

    if (l16 == 0) {
        #pragma unroll
        for (int t = 0; t < 2; ++t)
            #pragma unroll
            for (int r = 0; r < 4; ++r)
                EpP[jb * NB + ri + 16 * t + 4 * q + r] = E[t * 4 + r];
    }
}

__global__ __launch_bounds__(256) void finalize_kernel(
    const unsigned short* __restrict__ G,
    const float* __restrict__ EpP, const float* __restrict__ Sp,
    const unsigned char* __restrict__ cls, const int* __restrict__ cntP,
    float* __restrict__ out)
{
    __shared__ float SL[4 * 132];   // class sums, padded stride
    __shared__ int   cntL[4];
    __shared__ float wsum[4];
    const int tid = threadIdx.x;

    // Stage S (sum 64 partials per (c,dim)) and the class histogram.
    #pragma unroll
    for (int pp = 0; pp < 2; ++pp) {
        const int p = tid + pp * 256;  // p = c*128 + d, 512 entries
        float s = 0.f;
        for (int h = 0; h < 64; ++h) s += Sp[h * 512 + p];
        SL[(p >> 7) * 132 + (p & 127)] = s;
    }
    if (tid < 4) {
        int s = 0;
        for (int h = 0; h < HISTB; ++h) s += cntP[h * 4 + tid];
        cntL[tid] = s;
    }
    __syncthreads();

    const int i = blockIdx.x * 256 + tid;
    const int c = cls[i];
    const int pcnt = cntL[c ^ 1];
    const int ncnt = cntL[c ^ 2];

    float E = 0.f;
    #pragma unroll
    for (int jb = 0; jb < JSPLIT; ++jb) E += EpP[jb * NB + i];

    // Ls = g_i . S_{c^1}
    const unsigned short* gr = G + i * ND;
    const float* sv = SL + (c ^ 1) * 132;
    float ls = 0.f;
    #pragma unroll
    for (int v = 0; v < 16; ++v) {
        const short8 g8 = *(const short8*)(gr + v * 8);
        #pragma unroll
        for (int e = 0; e < 8; ++e)
            ls += bf2f((unsigned short)g8[e]) * sv[v * 8 + e];
    }

    float contrib = 0.f;
    if (pcnt > 0 && ncnt > 0)
        contrib = -(10.0f * ls - (float)pcnt * logf(E)) / ((float)pcnt * (float)NB);

    #pragma unroll
    for (int m = 1; m < 64; m <<= 1) contrib += __shfl_xor(contrib, m, 64);
    if ((tid & 63) == 0) wsum[tid >> 6] = contrib;
    __syncthreads();
    if (tid == 0) atomicAdd(out, wsum[0] + wsum[1] + wsum[2] + wsum[3]);
}

extern "C" void kernel_launch(void* const* d_in, const int* in_sizes, int n_in,
                              void* d_out, int out_size, void* d_ws, size_t ws_size,
                              hipStream_t stream) {
    const float* F  = (const float*)d_in[0];
    const int* dix  = (const int*)d_in[1];
    const int* tt   = (const int*)d_in[2];
    const int* tp   = (const int*)d_in[3];
    float* out = (float*)d_out;

    char* ws = (char*)d_ws;
    unsigned short* G  = (unsigned short*)(ws + OFF_G);
    float* EpP         = (float*)(ws + OFF_EPP);
    float* Sp          = (float*)(ws + OFF_SP);
    unsigned char* cls = (unsigned char*)(ws + OFF_CLS);
    int* cntP          = (int*)(ws + OFF_CNT);

    prep_kernel<<<2048 + HISTB, 256, 0, stream>>>(F, dix, tt, tp, G, cls, cntP, out);
    sim_kernel<<<SIMB + CSB, 256, 0, stream>>>(G, cls, EpP, Sp);
    finalize_kernel<<<NB / 256, 256, 0, stream>>>(G, EpP, Sp, cls, cntP, out);
}

// Round 4
// 164.303 us; speedup vs baseline: 1.2419x; 1.2419x over previous
//
#include <hip/hip_runtime.h>

// ContrastiveLoss: B=8192, D=128, T=0.1, SINGLE_POS=False.
// Algebra (verified in R3, absmax 0):
//   b = tt ^ tp.  pos|neg(i,j) <=> b_i != b_j.   E_i = sum_{b_j!=b_i} exp(10*s_ij).
//   Ls_i = g_i . S_{c_i^1} (class-sum vectors).  loss = -(1/B) sum_i valid*(10Ls - p*log E)/p.
// R4 structure: stable-sort rows by b; pure i-tiles scan only the opposite
// bucket (~half the columns) -> half the MFMA + half the exp. Per-element
// class mask kept everywhere => j-range restriction is pure work-skipping.
// R3 lesson: NO min-waves launch_bounds clamp (VGPR 40 forced A-fragment
// scratch spill: WRITE_SIZE 257 MB, sim 141 us).

#define NB 8192
#define ND 128
#define EXPK 14.426950408889634f   // 10 * log2(e)

#define NIT 64               // i-tiles of 128 rows
#define NSLOT 34             // j-slot partitions (128 cols each), slot-strided
#define SIMB (NIT * NSLOT)   // 2176 sim blocks
#define CSB 32               // fused class-sum blocks

typedef __attribute__((ext_vector_type(8))) short short8;
typedef __attribute__((ext_vector_type(4))) float f32x4;

// ws layout (bytes), total ~3.20 MB (R3 used 3.29 MB OK)
#define OFF_G    0                          // 8192*128 bf16 = 2 MB (PERMUTED rows)
#define OFF_EPP  2097152                    // 34*8192 f32 = 1114112
#define OFF_SP   3211264                    // 64*512 f32 = 131072 (class-sum partials)
#define OFF_CLS  3342336                    // 8192 u8 (unpermuted cls)
#define OFF_CLSP 3350528                    // 8192 u8 (permuted cls)
#define OFF_CNT  3358720                    // 32*4 i32 hist partials
#define OFF_BCNT 3359232                    // 32 i32 per-chunk b0 counts
#define OFF_N0   3359360                    // 1 i32

__device__ __forceinline__ unsigned short f2bf(float x) {
    unsigned int u = __float_as_uint(x);
    return (unsigned short)((u + 0x7FFFu + ((u >> 16) & 1u)) >> 16);  // RNE
}
__device__ __forceinline__ float bf2f(unsigned short h) {
    return __uint_as_float(((unsigned int)h) << 16);
}
__device__ __forceinline__ float fast_exp2(float x) {
#if __has_builtin(__builtin_amdgcn_exp2f)
    return __builtin_amdgcn_exp2f(x);
#else
    return exp2f(x);
#endif
}

// 32 blocks x 256 rows: label gather + LDS hist -> class/b-count partials.
__global__ __launch_bounds__(256) void prep_kernel(
    const int* __restrict__ dix, const int* __restrict__ tt,
    const int* __restrict__ tp, unsigned char* __restrict__ cls,
    int* __restrict__ cntP, int* __restrict__ bcnt0, float* __restrict__ out)
{
    __shared__ int lh[4];
    const int h = blockIdx.x, tid = threadIdx.x;
    if (tid < 4) lh[tid] = 0;
    __syncthreads();
    const int row = h * 256 + tid;
    const int ix  = dix[row];
    const int c   = ((tt[ix] & 1) << 1) | (tp[ix] & 1);
    cls[row] = (unsigned char)c;
    atomicAdd(&lh[c], 1);
    __syncthreads();
    if (tid < 4) cntP[h * 4 + tid] = lh[tid];
    if (tid == 4) bcnt0[h] = lh[0] + lh[3];     // b = (c>>1)^(c&1); c in {0,3} -> b=0
    if (h == 0 && tid == 5) *out = 0.0f;
}

// 32 blocks x 256 rows: normalize (wave-per-row in LDS), stable b-sort dest,
// scatter bf16 rows into permuted G + permuted cls. Block 0 stores N0.
__global__ __launch_bounds__(256) void permute_kernel(
    const float* __restrict__ F, const unsigned char* __restrict__ cls,
    const int* __restrict__ bcnt0, unsigned short* __restrict__ G,
    unsigned char* __restrict__ clsP, int* __restrict__ n0dev)
{
    __shared__ float invl[256];
    __shared__ int   dest[256];
    __shared__ int   woff[4];
    __shared__ int   base0, base1;
    const int h = blockIdx.x, tid = threadIdx.x;
    const int wave = tid >> 6, lane = tid & 63;

    // norms: each wave reduces 64 of the chunk's 256 rows
    for (int it = 0; it < 64; ++it) {
        const int rl = wave * 64 + it;
        const float2 v = *(const float2*)(F + (h * 256 + rl) * ND + lane * 2);
        float ss = v.x * v.x + v.y * v.y;
        #pragma unroll
        for (int m = 1; m < 64; m <<= 1) ss += __shfl_xor(ss, m, 64);
        if (lane == 0) invl[rl] = rsqrtf(fmaxf(ss, 1e-24f));
    }

    if (tid == 0) {
        int p = 0, tot = 0;
        for (int g = 0; g < 32; ++g) { const int b = bcnt0[g]; if (g < h) p += b; tot += b; }
        base0 = p;                       // global start of this chunk's b0 rows
        base1 = tot + h * 256 - p;       // N0 + (prior rows) - (prior b0)
        if (h == 0) *n0dev = tot;
    }
    __syncthreads();

    const int c = cls[h * 256 + tid];
    const int b = ((c >> 1) ^ c) & 1;
    const unsigned long long m = __ballot(b == 0);
    const int r0 = __popcll(m & ((1ull << lane) - 1ull));
    if (lane == 63) woff[wave] = __popcll(m);
    __syncthreads();
    int p0 = 0;
    #pragma unroll
    for (int w = 0; w < 4; ++w) p0 += (w < wave) ? woff[w] : 0;
    const int d = (b == 0) ? (base0 + p0 + r0)
                           : (base1 + (wave * 64 - p0) + (lane - r0));
    dest[tid] = d;
    clsP[d] = (unsigned char)c;
    __syncthreads();

    // scatter: 4 rows x 64 lanes x 2 dims per iteration
    const int rr = tid >> 6;
    const int d2 = (tid & 63) * 2;
    for (int rl = 0; rl < 256; rl += 4) {
        const int lr = rl + rr;
        const float2 v = *(const float2*)(F + (h * 256 + lr) * ND + d2);
        const float s = invl[lr];
        ushort2 st;
        st.x = f2bf(v.x * s);
        st.y = f2bf(v.y * s);
        *(ushort2*)(G + dest[lr] * ND + d2) = st;
    }
}

// Blocks 0..SIMB-1: i-tile = blk&63, slot = blk>>6. Pure tiles scan only the
// opposite-b column range; the (<=1) straddle tile scans all. Slot-strided
// range loop is correct for ANY N0. Per-element mask kept (R3-verified).
// Blocks SIMB..+CSB: class-sum S_c partials over permuted rows.
__global__ __launch_bounds__(256) void sim_kernel(
    const unsigned short* __restrict__ G,
    const unsigned char* __restrict__ clsP,
    const int* __restrict__ n0dev,
    float* __restrict__ EpP, float* __restrict__ Sp)
{
    if (blockIdx.x >= SIMB) {
        const int bk   = blockIdx.x - SIMB;
        const int dim  = threadIdx.x & 127;
        const int half = threadIdx.x >> 7;
        const int base = bk * 256 + half * 128;
        float a0 = 0.f, a1 = 0.f, a2 = 0.f, a3 = 0.f;
        for (int k = 0; k < 128; ++k) {
            const int row = base + k;
            const float g = bf2f(G[row * ND + dim]);
            const int c = clsP[row];
            a0 += (c == 0) ? g : 0.f;
            a1 += (c == 1) ? g : 0.f;
            a2 += (c == 2) ? g : 0.f;
            a3 += (c == 3) ? g : 0.f;
        }
        float* s = Sp + (bk * 2 + half) * 512 + dim;
        s[0] = a0; s[128] = a1; s[256] = a2; s[384] = a3;
        return;
    }

    const int it   = blockIdx.x & 63;
    const int slot = blockIdx.x >> 6;
    const int wave = threadIdx.x >> 6;
    const int lane = threadIdx.x & 63;
    const int q    = lane >> 4;
    const int l16  = lane & 15;
    const int ri   = it * 128 + wave * 32;

    // A-fragments resident: A[m=l16][k=q*8+j], chunk c covers k in [32c,32c+32)
    short8 A[2][4];
    #pragma unroll
    for (int t = 0; t < 2; ++t)
        #pragma unroll
        for (int c = 0; c < 4; ++c)
            A[t][c] = *(const short8*)(G + (ri + 16 * t + l16) * ND + c * 32 + q * 8);

    int B8 = 0;
    #pragma unroll
    for (int t = 0; t < 2; ++t)
        #pragma unroll
        for (int r = 0; r < 4; ++r) {
            const int ci = clsP[ri + 16 * t + 4 * q + r];
            B8 |= (((ci + 1) >> 1) & 1) << (t * 4 + r);
        }

    const int N0 = *n0dev;
    const int rbeg = it * 128;
    int jlo, nr;
    if (rbeg + 128 <= N0)      { jlo = N0 & ~127; nr = (NB - jlo) >> 7; }  // pure b0 -> scan b1 side
    else if (rbeg >= N0)       { jlo = 0;         nr = (N0 + 127) >> 7; } // pure b1 -> scan b0 side
    else                       { jlo = 0;         nr = NB >> 7; }          // straddle -> scan all

    float E[8];
    #pragma unroll
    for (int i = 0; i < 8; ++i) E[i] = 0.f;

    for (int rng = slot; rng < nr; rng += NSLOT) {
        const int cb = jlo + rng * 128;
        for (int k = 0; k < 8; ++k) {
            const int j0 = cb + k * 16;
            short8 Bf[4];
            #pragma unroll
            for (int c = 0; c < 4; ++c)
                Bf[c] = *(const short8*)(G + (j0 + l16) * ND + c * 32 + q * 8);
            const int c8 = clsP[j0 + l16];
            const int X  = B8 ^ (((c8 + 1) & 2) ? 255 : 0);  // bit set <=> b_i != b_j

            #pragma unroll
            for (int t = 0; t < 2; ++t) {
                f32x4 acc = {0.f, 0.f, 0.f, 0.f};
                #pragma unroll
                for (int c = 0; c < 4; ++c)
                    acc = __builtin_amdgcn_mfma_f32_16x16x32_bf16(A[t][c], Bf[c], acc, 0, 0, 0);
                #pragma unroll
                for (int r = 0; r < 4; ++r) {
                    const float e = fast_exp2(acc[r] * EXPK);
                    const int idx = t * 4 + r;
                    E[idx] += (X & (1 << idx)) ? e : 0.f;
                }
            }
        }
    }

    #pragma unroll
    for (int m = 1; m < 16; m <<= 1)
        #pragma unroll
        for (int i = 0; i < 8; ++i) E[i] += __shfl_xor(E[i], m, 64);

    if (l16 == 0) {   // ALWAYS store (ws is poisoned 0xAA; empty loops store 0)
        #pragma unroll
        for (int t = 0; t < 2; ++t)
            #pragma unroll
            for (int r = 0; r < 4; ++r)
                EpP[slot * NB + ri + 16 * t + 4 * q + r] = E[t * 4 + r];
    }
}

__global__ __launch_bounds__(256) void finalize_kernel(
    const unsigned short* __restrict__ G,
    const float* __restrict__ EpP, const float* __restrict__ Sp,
    const unsigned char* __restrict__ clsP, const int* __restrict__ cntP,
    float* __restrict__ out)
{
    __shared__ float SL[4 * 132];
    __shared__ int   cntL[4];
    __shared__ float wsum[4];
    const int tid = threadIdx.x;

    #pragma unroll
    for (int pp = 0; pp < 2; ++pp) {
        const int p = tid + pp * 256;  // p = c*128 + d
        float s = 0.f;
        for (int h = 0; h < 64; ++h) s += Sp[h * 512 + p];
        SL[(p >> 7) * 132 + (p & 127)] = s;
    }
    if (tid < 4) {
        int s = 0;
        for (int h = 0; h < 32; ++h) s += cntP[h * 4 + tid];
        cntL[tid] = s;
    }
    __syncthreads();

    const int i = blockIdx.x * 256 + tid;
    const int c = clsP[i];
    const int pcnt = cntL[c ^ 1];
    const int ncnt = cntL[c ^ 2];

    float E = 0.f;
    #pragma unroll
    for (int jb = 0; jb < NSLOT; ++jb) E += EpP[jb * NB + i];

    const unsigned short* gr = G + i * ND;
    const float* sv = SL + (c ^ 1) * 132;
    float ls = 0.f;
    #pragma unroll
    for (int v = 0; v < 16; ++v) {
        const short8 g8 = *(const short8*)(gr + v * 8);
        #pragma unroll
        for (int e = 0; e < 8; ++e)
            ls += bf2f((unsigned short)g8[e]) * sv[v * 8 + e];
    }

    float contrib = 0.f;
    if (pcnt > 0 && ncnt > 0)
        contrib = -(10.0f * ls - (float)pcnt * logf(E)) / ((float)pcnt * (float)NB);

    #pragma unroll
    for (int m = 1; m < 64; m <<= 1) contrib += __shfl_xor(contrib, m, 64);
    if ((tid & 63) == 0) wsum[tid >> 6] = contrib;
    __syncthreads();
    if (tid == 0) atomicAdd(out, wsum[0] + wsum[1] + wsum[2] + wsum[3]);
}

extern "C" void kernel_launch(void* const* d_in, const int* in_sizes, int n_in,
                              void* d_out, int out_size, void* d_ws, size_t ws_size,
                              hipStream_t stream) {
    const float* F  = (const float*)d_in[0];
    const int* dix  = (const int*)d_in[1];
    const int* tt   = (const int*)d_in[2];
    const int* tp   = (const int*)d_in[3];
    float* out = (float*)d_out;

    char* ws = (char*)d_ws;
    unsigned short* G   = (unsigned short*)(ws + OFF_G);
    float* EpP          = (float*)(ws + OFF_EPP);
    float* Sp           = (float*)(ws + OFF_SP);
    unsigned char* cls  = (unsigned char*)(ws + OFF_CLS);
    unsigned char* clsP = (unsigned char*)(ws + OFF_CLSP);
    int* cntP           = (int*)(ws + OFF_CNT);
    int* bcnt0          = (int*)(ws + OFF_BCNT);
    int* n0dev          = (int*)(ws + OFF_N0);

    prep_kernel<<<32, 256, 0, stream>>>(dix, tt, tp, cls, cntP, bcnt0, out);
    permute_kernel<<<32, 256, 0, stream>>>(F, cls, bcnt0, G, clsP, n0dev);
    sim_kernel<<<SIMB + CSB, 256, 0, stream>>>(G, clsP, n0dev, EpP, Sp);
    finalize_kernel<<<NB / 256, 256, 0, stream>>>(G, EpP, Sp, clsP, cntP, out);
}